// Round 1
// baseline (1171.550 us; speedup 1.0000x reference)
//
#include <hip/hip_runtime.h>
#include <math.h>

// Problem constants (from reference)
#define Bb 4
#define Ss 2048
#define Hh 1024
#define Ee 8
#define Kk 512
#define Ff 4096

typedef short bf16x8 __attribute__((ext_vector_type(8)));       // 8 bf16 in 4 VGPRs
typedef unsigned short u16x8 __attribute__((ext_vector_type(8)));
typedef float f32x4 __attribute__((ext_vector_type(4)));

// fp32 -> bf16 round-to-nearest-even (bit form)
__device__ __forceinline__ unsigned short f2bf(float f) {
    unsigned int u = __float_as_uint(f);
    u = (u + 0x7FFFu + ((u >> 16) & 1u)) >> 16;
    return (unsigned short)u;
}

// ---------------------------------------------------------------------------
// 1) Gating: logits = x . Wg[e], softmax over E (fp64 accumulation so the
//    top-K boundary ranking matches the numpy reference; gaps ~1e-4 >> err)
//    One wave per token. Sm layout: [B,E,S] fp32.
// ---------------------------------------------------------------------------
__global__ __launch_bounds__(256) void gating_kernel(
    const float* __restrict__ x, const float* __restrict__ wg,
    float* __restrict__ Sm)
{
    int wave = threadIdx.x >> 6;
    int lane = threadIdx.x & 63;
    int token = blockIdx.x * 4 + wave;            // 0 .. B*S-1
    int b = token >> 11, s = token & (Ss - 1);
    const float* xr = x + (size_t)token * Hh;

    double acc[Ee];
#pragma unroll
    for (int e = 0; e < Ee; ++e) acc[e] = 0.0;

    for (int i = 0; i < Hh / 64; ++i) {
        int h = lane + i * 64;
        double xv = (double)xr[h];
#pragma unroll
        for (int e = 0; e < Ee; ++e)
            acc[e] += xv * (double)wg[e * Hh + h];
    }
    // butterfly reduce across the 64-lane wave
#pragma unroll
    for (int off = 32; off; off >>= 1) {
#pragma unroll
        for (int e = 0; e < Ee; ++e)
            acc[e] += __shfl_xor(acc[e], off, 64);
    }
    if (lane < Ee) {
        double m = acc[0];
#pragma unroll
        for (int e = 1; e < Ee; ++e) m = acc[e] > m ? acc[e] : m;
        double sum = 0.0;
#pragma unroll
        for (int e = 0; e < Ee; ++e) sum += exp(acc[e] - m);
        double v = exp(acc[lane] - m) / sum;
        Sm[((size_t)(b * Ee + lane)) * Ss + s] = (float)v;
    }
}

// ---------------------------------------------------------------------------
// 2) Top-K per (b,e) row: bitonic sort of 2048 64-bit keys in LDS.
//    key = (float_bits << 32) | (0xFFFFFFFF - index): descending value,
//    ties -> lower index first (matches jax.lax.top_k).
// ---------------------------------------------------------------------------
__global__ __launch_bounds__(1024) void topk_kernel(
    const float* __restrict__ Sm, int* __restrict__ I, float* __restrict__ G)
{
    __shared__ unsigned long long keys[Ss];
    int be = blockIdx.x;
    const float* row = Sm + (size_t)be * Ss;
    for (int i = threadIdx.x; i < Ss; i += 1024) {
        unsigned int vb = __float_as_uint(row[i]);     // softmax > 0 -> monotonic bits
        keys[i] = ((unsigned long long)vb << 32) | (unsigned int)(0xFFFFFFFFu - i);
    }
    __syncthreads();
    for (int k = 2; k <= Ss; k <<= 1) {
        for (int j = k >> 1; j > 0; j >>= 1) {
            for (int i = threadIdx.x; i < Ss; i += 1024) {
                int ixj = i ^ j;
                if (ixj > i) {
                    unsigned long long a = keys[i], c = keys[ixj];
                    bool desc = ((i & k) == 0);
                    if (desc ? (a < c) : (a > c)) { keys[i] = c; keys[ixj] = a; }
                }
            }
            __syncthreads();
        }
    }
    if (threadIdx.x < Kk) {
        unsigned long long kk = keys[threadIdx.x];
        I[(size_t)be * Kk + threadIdx.x] = (int)(0xFFFFFFFFu - (unsigned int)(kk & 0xFFFFFFFFu));
        G[(size_t)be * Kk + threadIdx.x] = __uint_as_float((unsigned int)(kk >> 32));
    }
}

// ---------------------------------------------------------------------------
// 3) Transpose + cast fp32 -> bf16.  dst[z][c][r] = src[z][r][c]
// ---------------------------------------------------------------------------
__global__ __launch_bounds__(256) void transpose_cast_kernel(
    const float* __restrict__ src, unsigned short* __restrict__ dst, int R, int C)
{
    __shared__ float tile[32][33];
    int z = blockIdx.z;
    const float* s = src + (size_t)z * R * C;
    unsigned short* d = dst + (size_t)z * R * C;
    int c0 = blockIdx.x * 32, r0 = blockIdx.y * 32;
    for (int i = threadIdx.y; i < 32; i += 8)
        tile[i][threadIdx.x] = s[(size_t)(r0 + i) * C + c0 + threadIdx.x];
    __syncthreads();
    for (int i = threadIdx.y; i < 32; i += 8)
        d[(size_t)(c0 + i) * R + r0 + threadIdx.x] = f2bf(tile[threadIdx.x][i]);
}

// ---------------------------------------------------------------------------
// GEMM common: 64x64 block tile, 256 threads = 4 waves, each wave a 32x32
// region via 2x2 MFMA 16x16x32 bf16.  LDS tiles [64 rows][32 k] padded to 40.
// Fragment maps (HW-verified): A/B [m|n = lane&15][k = quad*8+j],
// C/D col = lane&15, row = quad*4 + reg.
// ---------------------------------------------------------------------------
#define LDK 40

__global__ __launch_bounds__(256) void gemm1_kernel(
    const float* __restrict__ x, const unsigned short* __restrict__ w1t, // [E,F,H] bf16
    const float* __restrict__ b1, const int* __restrict__ I,
    unsigned short* __restrict__ h1, int b)   // h1: [E,K,F] bf16 (per-b buffer)
{
    const int e = blockIdx.z;
    const int tn = blockIdx.x, tm = blockIdx.y;
    __shared__ unsigned short As[64 * LDK];
    __shared__ unsigned short Bs[64 * LDK];
    const int tid = threadIdx.x;
    const int lane = tid & 63, wave = tid >> 6;
    const int wm = (wave & 1) * 32, wn = (wave >> 1) * 32;
    const int fr = lane & 15, quad = lane >> 4;

    const int srow = tid >> 2, skp = (tid & 3) * 8;
    const int tok = I[(b * Ee + e) * Kk + tm * 64 + srow];
    const float* xrow = x + ((size_t)(b * Ss + tok)) * Hh;
    const unsigned short* brow = w1t + ((size_t)e * Ff + tn * 64 + srow) * Hh;

    f32x4 acc[2][2] = {};
    for (int k0 = 0; k0 < Hh; k0 += 32) {
        float4 a0 = *(const float4*)(xrow + k0 + skp);
        float4 a1 = *(const float4*)(xrow + k0 + skp + 4);
        uint4 bv = *(const uint4*)(brow + k0 + skp);
        u16x8 av;
        av[0] = f2bf(a0.x); av[1] = f2bf(a0.y); av[2] = f2bf(a0.z); av[3] = f2bf(a0.w);
        av[4] = f2bf(a1.x); av[5] = f2bf(a1.y); av[6] = f2bf(a1.z); av[7] = f2bf(a1.w);
        *(u16x8*)(&As[srow * LDK + skp]) = av;
        *(uint4*)(&Bs[srow * LDK + skp]) = bv;
        __syncthreads();
        bf16x8 af0 = *(const bf16x8*)(&As[(wm + fr) * LDK + quad * 8]);
        bf16x8 af1 = *(const bf16x8*)(&As[(wm + 16 + fr) * LDK + quad * 8]);
        bf16x8 bf0 = *(const bf16x8*)(&Bs[(wn + fr) * LDK + quad * 8]);
        bf16x8 bf1 = *(const bf16x8*)(&Bs[(wn + 16 + fr) * LDK + quad * 8]);
        acc[0][0] = __builtin_amdgcn_mfma_f32_16x16x32_bf16(af0, bf0, acc[0][0], 0, 0, 0);
        acc[0][1] = __builtin_amdgcn_mfma_f32_16x16x32_bf16(af0, bf1, acc[0][1], 0, 0, 0);
        acc[1][0] = __builtin_amdgcn_mfma_f32_16x16x32_bf16(af1, bf0, acc[1][0], 0, 0, 0);
        acc[1][1] = __builtin_amdgcn_mfma_f32_16x16x32_bf16(af1, bf1, acc[1][1], 0, 0, 0);
        __syncthreads();
    }
#pragma unroll
    for (int i = 0; i < 2; ++i)
#pragma unroll
        for (int j = 0; j < 2; ++j) {
            int nn = tn * 64 + wn + j * 16 + fr;
            float bias = b1[e * Ff + nn];
#pragma unroll
            for (int r = 0; r < 4; ++r) {
                int mm = tm * 64 + wm + i * 16 + quad * 4 + r;
                float v = acc[i][j][r] + bias;
                // jax.nn.gelu default: tanh approximation
                float u = 0.7978845608028654f * (v + 0.044715f * v * v * v);
                float g = 0.5f * v * (1.0f + tanhf(u));
                h1[((size_t)e * Kk + mm) * Ff + nn] = f2bf(g);
            }
        }
}

__global__ __launch_bounds__(256) void gemm2_kernel(
    const unsigned short* __restrict__ h1, const unsigned short* __restrict__ w2t, // [E,H,F] bf16
    const float* __restrict__ b2, const int* __restrict__ I, const float* __restrict__ G,
    float* __restrict__ out, int b)
{
    const int e = blockIdx.z;
    const int tn = blockIdx.x, tm = blockIdx.y;
    __shared__ unsigned short As[64 * LDK];
    __shared__ unsigned short Bs[64 * LDK];
    const int tid = threadIdx.x;
    const int lane = tid & 63, wave = tid >> 6;
    const int wm = (wave & 1) * 32, wn = (wave >> 1) * 32;
    const int fr = lane & 15, quad = lane >> 4;

    const int srow = tid >> 2, skp = (tid & 3) * 8;
    const unsigned short* arow = h1 + ((size_t)e * Kk + tm * 64 + srow) * Ff;
    const unsigned short* brow = w2t + ((size_t)e * Hh + tn * 64 + srow) * Ff;

    f32x4 acc[2][2] = {};
    for (int k0 = 0; k0 < Ff; k0 += 32) {
        uint4 av = *(const uint4*)(arow + k0 + skp);
        uint4 bv = *(const uint4*)(brow + k0 + skp);
        *(uint4*)(&As[srow * LDK + skp]) = av;
        *(uint4*)(&Bs[srow * LDK + skp]) = bv;
        __syncthreads();
        bf16x8 af0 = *(const bf16x8*)(&As[(wm + fr) * LDK + quad * 8]);
        bf16x8 af1 = *(const bf16x8*)(&As[(wm + 16 + fr) * LDK + quad * 8]);
        bf16x8 bf0 = *(const bf16x8*)(&Bs[(wn + fr) * LDK + quad * 8]);
        bf16x8 bf1 = *(const bf16x8*)(&Bs[(wn + 16 + fr) * LDK + quad * 8]);
        acc[0][0] = __builtin_amdgcn_mfma_f32_16x16x32_bf16(af0, bf0, acc[0][0], 0, 0, 0);
        acc[0][1] = __builtin_amdgcn_mfma_f32_16x16x32_bf16(af0, bf1, acc[0][1], 0, 0, 0);
        acc[1][0] = __builtin_amdgcn_mfma_f32_16x16x32_bf16(af1, bf0, acc[1][0], 0, 0, 0);
        acc[1][1] = __builtin_amdgcn_mfma_f32_16x16x32_bf16(af1, bf1, acc[1][1], 0, 0, 0);
        __syncthreads();
    }
#pragma unroll
    for (int i = 0; i < 2; ++i)
#pragma unroll
        for (int j = 0; j < 2; ++j) {
            int nn = tn * 64 + wn + j * 16 + fr;
            float bias = b2[e * Hh + nn];
#pragma unroll
            for (int r = 0; r < 4; ++r) {
                int mm = tm * 64 + wm + i * 16 + quad * 4 + r;
                int slot = (b * Ee + e) * Kk + mm;
                float gate = G[slot];
                int tok = I[slot];
                float v = (acc[i][j][r] + bias) * gate;
                atomicAdd(&out[((size_t)(b * Ss + tok)) * Hh + nn], v);
            }
        }
}

// ---------------------------------------------------------------------------
extern "C" void kernel_launch(void* const* d_in, const int* in_sizes, int n_in,
                              void* d_out, int out_size, void* d_ws, size_t ws_size,
                              hipStream_t stream) {
    const float* x  = (const float*)d_in[0];   // [B,S,H]
    const float* Wg = (const float*)d_in[1];   // [E,H]
    const float* W1 = (const float*)d_in[2];   // [E,H,F]
    const float* b1 = (const float*)d_in[3];   // [E,F]
    const float* W2 = (const float*)d_in[4];   // [E,F,H]
    const float* b2 = (const float*)d_in[5];   // [E,H]
    float* out = (float*)d_out;                // [B,S,H]

    // workspace carve-up (~168.2 MB total)
    size_t off = 0;
    char* base = (char*)d_ws;
    auto alloc = [&](size_t bytes) -> void* {
        void* p = base + off;
        off += (bytes + 255) & ~(size_t)255;
        return p;
    };
    float* Sm  = (float*)alloc((size_t)Bb * Ee * Ss * 4);
    int*   I   = (int*)alloc((size_t)Bb * Ee * Kk * 4);
    float* G   = (float*)alloc((size_t)Bb * Ee * Kk * 4);
    unsigned short* W1T = (unsigned short*)alloc((size_t)Ee * Ff * Hh * 2); // [E,F,H]
    unsigned short* W2T = (unsigned short*)alloc((size_t)Ee * Hh * Ff * 2); // [E,H,F]
    unsigned short* h1  = (unsigned short*)alloc((size_t)Ee * Kk * Ff * 2); // per-b [E,K,F]
    if (off > ws_size) return;  // workspace too small -> out stays zero (diagnosable)

    hipMemsetAsync(d_out, 0, (size_t)out_size * sizeof(float), stream);

    gating_kernel<<<(Bb * Ss) / 4, 256, 0, stream>>>(x, Wg, Sm);
    topk_kernel<<<Bb * Ee, 1024, 0, stream>>>(Sm, I, G);
    transpose_cast_kernel<<<dim3(Ff / 32, Hh / 32, Ee), dim3(32, 8), 0, stream>>>(W1, W1T, Hh, Ff);
    transpose_cast_kernel<<<dim3(Hh / 32, Ff / 32, Ee), dim3(32, 8), 0, stream>>>(W2, W2T, Ff, Hh);

    for (int b = 0; b < Bb; ++b) {
        gemm1_kernel<<<dim3(Ff / 64, Kk / 64, Ee), 256, 0, stream>>>(x, W1T, b1, I, h1, b);
        gemm2_kernel<<<dim3(Hh / 64, Kk / 64, Ee), 256, 0, stream>>>(h1, W2T, b2, I, G, out, b);
    }
}

// Round 2
// 1004.496 us; speedup vs baseline: 1.1663x; 1.1663x over previous
//
#include <hip/hip_runtime.h>
#include <math.h>
#include <cstdint>

// Problem constants (from reference)
#define Bb 4
#define Ss 2048
#define Hh 1024
#define Ee 8
#define Kk 512
#define Ff 4096

typedef short bf16x8 __attribute__((ext_vector_type(8)));       // 8 bf16 in 4 VGPRs
typedef float f32x4 __attribute__((ext_vector_type(4)));

// fp32 -> bf16 round-to-nearest-even (bit form)
__device__ __forceinline__ unsigned short f2bf(float f) {
    unsigned int u = __float_as_uint(f);
    u = (u + 0x7FFFu + ((u >> 16) & 1u)) >> 16;
    return (unsigned short)u;
}

// async 16B global->LDS copy (global_load_lds_dwordx4). LDS dest is
// wave-uniform base + lane*16 (m104/m108): pass a wave-uniform lds ptr.
__device__ __forceinline__ void async_copy16(const void* gsrc, void* ldst) {
    auto* g = reinterpret_cast<__attribute__((address_space(1))) void*>(
        reinterpret_cast<uintptr_t>(gsrc));
    auto* l = reinterpret_cast<__attribute__((address_space(3))) void*>(
        (unsigned int)reinterpret_cast<uintptr_t>(ldst));   // low32 of flat = LDS offset
    __builtin_amdgcn_global_load_lds(g, l, 16, 0, 0);
}

// ---------------------------------------------------------------------------
// 0) x fp32 -> bf16 cast (so gemm1 A-gather can use global_load_lds)
// ---------------------------------------------------------------------------
__global__ __launch_bounds__(256) void cast_kernel(
    const float4* __restrict__ s, ushort4* __restrict__ d)
{
    int i = blockIdx.x * 256 + threadIdx.x;
    float4 v = s[i];
    ushort4 o;
    o.x = f2bf(v.x); o.y = f2bf(v.y); o.z = f2bf(v.z); o.w = f2bf(v.w);
    d[i] = o;
}

// ---------------------------------------------------------------------------
// 1) Gating: fp64 accumulation so the top-K boundary ranking matches numpy
// ---------------------------------------------------------------------------
__global__ __launch_bounds__(256) void gating_kernel(
    const float* __restrict__ x, const float* __restrict__ wg,
    float* __restrict__ Sm)
{
    int wave = threadIdx.x >> 6;
    int lane = threadIdx.x & 63;
    int token = blockIdx.x * 4 + wave;            // 0 .. B*S-1
    int b = token >> 11, s = token & (Ss - 1);
    const float* xr = x + (size_t)token * Hh;

    double acc[Ee];
#pragma unroll
    for (int e = 0; e < Ee; ++e) acc[e] = 0.0;

    for (int i = 0; i < Hh / 64; ++i) {
        int h = lane + i * 64;
        double xv = (double)xr[h];
#pragma unroll
        for (int e = 0; e < Ee; ++e)
            acc[e] += xv * (double)wg[e * Hh + h];
    }
#pragma unroll
    for (int off = 32; off; off >>= 1) {
#pragma unroll
        for (int e = 0; e < Ee; ++e)
            acc[e] += __shfl_xor(acc[e], off, 64);
    }
    if (lane < Ee) {
        double m = acc[0];
#pragma unroll
        for (int e = 1; e < Ee; ++e) m = acc[e] > m ? acc[e] : m;
        double sum = 0.0;
#pragma unroll
        for (int e = 0; e < Ee; ++e) sum += exp(acc[e] - m);
        double v = exp(acc[lane] - m) / sum;
        Sm[((size_t)(b * Ee + lane)) * Ss + s] = (float)v;
    }
}

// ---------------------------------------------------------------------------
// 2) Top-K per (b,e): bitonic sort of 2048 keys; ties -> lower index first
// ---------------------------------------------------------------------------
__global__ __launch_bounds__(1024) void topk_kernel(
    const float* __restrict__ Sm, int* __restrict__ I, float* __restrict__ G)
{
    __shared__ unsigned long long keys[Ss];
    int be = blockIdx.x;
    const float* row = Sm + (size_t)be * Ss;
    for (int i = threadIdx.x; i < Ss; i += 1024) {
        unsigned int vb = __float_as_uint(row[i]);
        keys[i] = ((unsigned long long)vb << 32) | (unsigned int)(0xFFFFFFFFu - i);
    }
    __syncthreads();
    for (int k = 2; k <= Ss; k <<= 1) {
        for (int j = k >> 1; j > 0; j >>= 1) {
            for (int i = threadIdx.x; i < Ss; i += 1024) {
                int ixj = i ^ j;
                if (ixj > i) {
                    unsigned long long a = keys[i], c = keys[ixj];
                    bool desc = ((i & k) == 0);
                    if (desc ? (a < c) : (a > c)) { keys[i] = c; keys[ixj] = a; }
                }
            }
            __syncthreads();
        }
    }
    if (threadIdx.x < Kk) {
        unsigned long long kk = keys[threadIdx.x];
        I[(size_t)be * Kk + threadIdx.x] = (int)(0xFFFFFFFFu - (unsigned int)(kk & 0xFFFFFFFFu));
        G[(size_t)be * Kk + threadIdx.x] = __uint_as_float((unsigned int)(kk >> 32));
    }
}

// ---------------------------------------------------------------------------
// 3) Transpose + cast fp32 -> bf16.  dst[z][c][r] = src[z][r][c]
// ---------------------------------------------------------------------------
__global__ __launch_bounds__(256) void transpose_cast_kernel(
    const float* __restrict__ src, unsigned short* __restrict__ dst, int R, int C)
{
    __shared__ float tile[32][33];
    int z = blockIdx.z;
    const float* s = src + (size_t)z * R * C;
    unsigned short* d = dst + (size_t)z * R * C;
    int c0 = blockIdx.x * 32, r0 = blockIdx.y * 32;
    for (int i = threadIdx.y; i < 32; i += 8)
        tile[i][threadIdx.x] = s[(size_t)(r0 + i) * C + c0 + threadIdx.x];
    __syncthreads();
    for (int i = threadIdx.y; i < 32; i += 8)
        d[(size_t)(c0 + i) * R + r0 + threadIdx.x] = f2bf(tile[threadIdx.x][i]);
}

// ---------------------------------------------------------------------------
// GEMM: 128x128 block tile, BK=32, 256 threads = 4 waves (2x2), each wave a
// 64x64 region via 4x4 MFMA 16x16x32 bf16 (m97 structure).
// LDS tiles row-major [128][32] bf16 (8KB each), unpadded (global_load_lds
// requires lane-ordered contiguous placement).
// Staging: granule a16 = issue*256 + tid covers row=a16>>2, elems (a16&3)*8.
// Fragments: A/B [m|n = lane&15][k = quad*8+j]; C/D col=lane&15, row=quad*4+r.
// ---------------------------------------------------------------------------
#define BM 128
#define BN 128
#define BK 32

__global__ __launch_bounds__(256) void gemm1_kernel(
    const unsigned short* __restrict__ xb,   // [B,S,H] bf16
    const unsigned short* __restrict__ w1t,  // [E,F,H] bf16
    const float* __restrict__ b1, const int* __restrict__ I,
    unsigned short* __restrict__ h1, int b)  // h1: [E,K,F] bf16 per-b
{
    __shared__ unsigned short As[BM * BK];   // 8 KB
    __shared__ unsigned short Bs[BN * BK];   // 8 KB
    const int e = blockIdx.z;
    const int tn = blockIdx.x, tm = blockIdx.y;
    const int t = threadIdx.x;
    const int lane = t & 63, w = t >> 6;
    const int wm = (w & 1) * 64, wn = (w >> 1) * 64;
    const int fr = lane & 15, quad = lane >> 4;

    const int srow = t >> 2, sc = (t & 3) * 8;   // staging row / elem offset
    const int ib = (b * Ee + e) * Kk + tm * BM;
    const int tok0 = I[ib + srow];
    const int tok1 = I[ib + srow + 64];
    const unsigned short* arow0 = xb + ((size_t)(b * Ss + tok0)) * Hh + sc;
    const unsigned short* arow1 = xb + ((size_t)(b * Ss + tok1)) * Hh + sc;
    const unsigned short* brow0 = w1t + ((size_t)e * Ff + tn * BN + srow) * Hh + sc;
    const unsigned short* brow1 = brow0 + (size_t)64 * Hh;
    char* asDst = (char*)As + w * 1024;          // wave-uniform LDS dst
    char* bsDst = (char*)Bs + w * 1024;

    f32x4 acc[4][4] = {};
    for (int k0 = 0; k0 < Hh; k0 += BK) {
        async_copy16(arow0 + k0, asDst);
        async_copy16(arow1 + k0, asDst + 4096);
        async_copy16(brow0 + k0, bsDst);
        async_copy16(brow1 + k0, bsDst + 4096);
        __syncthreads();
        bf16x8 a[4], bf[4];
#pragma unroll
        for (int i = 0; i < 4; ++i)
            a[i] = *(const bf16x8*)(&As[(wm + i * 16 + fr) * BK + quad * 8]);
#pragma unroll
        for (int j = 0; j < 4; ++j)
            bf[j] = *(const bf16x8*)(&Bs[(wn + j * 16 + fr) * BK + quad * 8]);
#pragma unroll
        for (int i = 0; i < 4; ++i)
#pragma unroll
            for (int j = 0; j < 4; ++j)
                acc[i][j] = __builtin_amdgcn_mfma_f32_16x16x32_bf16(a[i], bf[j], acc[i][j], 0, 0, 0);
        __syncthreads();
    }

    float bias[4];
#pragma unroll
    for (int j = 0; j < 4; ++j)
        bias[j] = b1[e * Ff + tn * BN + wn + j * 16 + fr];
#pragma unroll
    for (int i = 0; i < 4; ++i) {
#pragma unroll
        for (int r = 0; r < 4; ++r) {
            int mm = tm * BM + wm + i * 16 + quad * 4 + r;
            unsigned short* orow = h1 + ((size_t)e * Kk + mm) * Ff + tn * BN + wn + fr;
#pragma unroll
            for (int j = 0; j < 4; ++j) {
                float v = acc[i][j][r] + bias[j];
                float u = 0.7978845608028654f * (v + 0.044715f * v * v * v);
                float g = 0.5f * v * (1.0f + tanhf(u));
                orow[j * 16] = f2bf(g);
            }
        }
    }
}

#define KSPLIT 2
#define FH (Ff / KSPLIT)   // 2048

__global__ __launch_bounds__(256) void gemm2_kernel(
    const unsigned short* __restrict__ h1,   // [E,K,F] bf16 per-b
    const unsigned short* __restrict__ w2t,  // [E,H,F] bf16
    const float* __restrict__ b2, const int* __restrict__ I, const float* __restrict__ G,
    float* __restrict__ out, int b)
{
    __shared__ unsigned short As[BM * BK];
    __shared__ unsigned short Bs[BN * BK];
    const int e = blockIdx.z >> 1, kf = blockIdx.z & 1;
    const int tn = blockIdx.x, tm = blockIdx.y;
    const int t = threadIdx.x;
    const int lane = t & 63, w = t >> 6;
    const int wm = (w & 1) * 64, wn = (w >> 1) * 64;
    const int fr = lane & 15, quad = lane >> 4;

    const int srow = t >> 2, sc = (t & 3) * 8;
    const unsigned short* arow0 = h1 + ((size_t)e * Kk + tm * BM + srow) * Ff + kf * FH + sc;
    const unsigned short* arow1 = arow0 + (size_t)64 * Ff;
    const unsigned short* brow0 = w2t + ((size_t)e * Hh + tn * BN + srow) * Ff + kf * FH + sc;
    const unsigned short* brow1 = brow0 + (size_t)64 * Ff;
    char* asDst = (char*)As + w * 1024;
    char* bsDst = (char*)Bs + w * 1024;

    f32x4 acc[4][4] = {};
    for (int k0 = 0; k0 < FH; k0 += BK) {
        async_copy16(arow0 + k0, asDst);
        async_copy16(arow1 + k0, asDst + 4096);
        async_copy16(brow0 + k0, bsDst);
        async_copy16(brow1 + k0, bsDst + 4096);
        __syncthreads();
        bf16x8 a[4], bf[4];
#pragma unroll
        for (int i = 0; i < 4; ++i)
            a[i] = *(const bf16x8*)(&As[(wm + i * 16 + fr) * BK + quad * 8]);
#pragma unroll
        for (int j = 0; j < 4; ++j)
            bf[j] = *(const bf16x8*)(&Bs[(wn + j * 16 + fr) * BK + quad * 8]);
#pragma unroll
        for (int i = 0; i < 4; ++i)
#pragma unroll
            for (int j = 0; j < 4; ++j)
                acc[i][j] = __builtin_amdgcn_mfma_f32_16x16x32_bf16(a[i], bf[j], acc[i][j], 0, 0, 0);
        __syncthreads();
    }

    float bias[4];
#pragma unroll
    for (int j = 0; j < 4; ++j)
        bias[j] = (kf == 0) ? b2[e * Hh + tn * BN + wn + j * 16 + fr] : 0.0f;
#pragma unroll
    for (int i = 0; i < 4; ++i) {
#pragma unroll
        for (int r = 0; r < 4; ++r) {
            int mm = tm * BM + wm + i * 16 + quad * 4 + r;
            int slot = (b * Ee + e) * Kk + mm;
            float gate = G[slot];
            int tok = I[slot];
            float* orow = out + ((size_t)(b * Ss + tok)) * Hh + tn * BN + wn + fr;
#pragma unroll
            for (int j = 0; j < 4; ++j) {
                float v = (acc[i][j][r] + bias[j]) * gate;
                atomicAdd(&orow[j * 16], v);
            }
        }
    }
}

// ---------------------------------------------------------------------------
extern "C" void kernel_launch(void* const* d_in, const int* in_sizes, int n_in,
                              void* d_out, int out_size, void* d_ws, size_t ws_size,
                              hipStream_t stream) {
    const float* x  = (const float*)d_in[0];   // [B,S,H]
    const float* Wg = (const float*)d_in[1];   // [E,H]
    const float* W1 = (const float*)d_in[2];   // [E,H,F]
    const float* b1 = (const float*)d_in[3];   // [E,F]
    const float* W2 = (const float*)d_in[4];   // [E,F,H]
    const float* b2 = (const float*)d_in[5];   // [E,H]
    float* out = (float*)d_out;                // [B,S,H]

    // workspace carve-up (~179 MB total)
    size_t off = 0;
    char* base = (char*)d_ws;
    auto alloc = [&](size_t bytes) -> void* {
        void* p = base + off;
        off += (bytes + 255) & ~(size_t)255;
        return p;
    };
    float* Sm  = (float*)alloc((size_t)Bb * Ee * Ss * 4);
    int*   I   = (int*)alloc((size_t)Bb * Ee * Kk * 4);
    float* G   = (float*)alloc((size_t)Bb * Ee * Kk * 4);
    unsigned short* W1T = (unsigned short*)alloc((size_t)Ee * Ff * Hh * 2); // [E,F,H]
    unsigned short* W2T = (unsigned short*)alloc((size_t)Ee * Hh * Ff * 2); // [E,H,F]
    unsigned short* xb  = (unsigned short*)alloc((size_t)Bb * Ss * Hh * 2); // [B,S,H]
    unsigned short* h1  = (unsigned short*)alloc((size_t)Ee * Kk * Ff * 2); // per-b [E,K,F]
    if (off > ws_size) return;

    hipMemsetAsync(d_out, 0, (size_t)out_size * sizeof(float), stream);

    cast_kernel<<<(Bb * Ss * Hh) / 1024, 256, 0, stream>>>((const float4*)x, (ushort4*)xb);
    gating_kernel<<<(Bb * Ss) / 4, 256, 0, stream>>>(x, Wg, Sm);
    topk_kernel<<<Bb * Ee, 1024, 0, stream>>>(Sm, I, G);
    transpose_cast_kernel<<<dim3(Ff / 32, Hh / 32, Ee), dim3(32, 8), 0, stream>>>(W1, W1T, Hh, Ff);
    transpose_cast_kernel<<<dim3(Hh / 32, Ff / 32, Ee), dim3(32, 8), 0, stream>>>(W2, W2T, Ff, Hh);

    for (int b = 0; b < Bb; ++b) {
        gemm1_kernel<<<dim3(Ff / BN, Kk / BM, Ee), 256, 0, stream>>>(xb, W1T, b1, I, h1, b);
        gemm2_kernel<<<dim3(Hh / BN, Kk / BM, Ee * KSPLIT), 256, 0, stream>>>(h1, W2T, b2, I, G, out, b);
    }
}

// Round 3
// 834.132 us; speedup vs baseline: 1.4045x; 1.2042x over previous
//
#include <hip/hip_runtime.h>
#include <math.h>
#include <cstdint>

// Problem constants (from reference)
#define Bb 4
#define Ss 2048
#define Hh 1024
#define Ee 8
#define Kk 512
#define Ff 4096

typedef short bf16x8 __attribute__((ext_vector_type(8)));       // 8 bf16 in 4 VGPRs
typedef unsigned short u16x8 __attribute__((ext_vector_type(8)));
typedef float f32x4 __attribute__((ext_vector_type(4)));

// fp32 -> bf16 round-to-nearest-even (bit form)
__device__ __forceinline__ unsigned short f2bf(float f) {
    unsigned int u = __float_as_uint(f);
    u = (u + 0x7FFFu + ((u >> 16) & 1u)) >> 16;
    return (unsigned short)u;
}

// async 16B global->LDS copy (global_load_lds_dwordx4). LDS dest is
// wave-uniform base + lane*16 (m104/m108).
__device__ __forceinline__ void async_copy16(const void* gsrc, void* ldst) {
    auto* g = reinterpret_cast<__attribute__((address_space(1))) void*>(
        reinterpret_cast<uintptr_t>(gsrc));
    auto* l = reinterpret_cast<__attribute__((address_space(3))) void*>(
        (unsigned int)reinterpret_cast<uintptr_t>(ldst));
    __builtin_amdgcn_global_load_lds(g, l, 16, 0, 0);
}

// exact tanh-gelu via fast exp (no libcall)
__device__ __forceinline__ float gelu(float v) {
    float uu = 0.7978845608028654f * (v + 0.044715f * v * v * v);
    float t = __expf(-2.0f * fabsf(uu));
    float th = (1.0f - t) / (1.0f + t);
    th = copysignf(th, uu);
    return 0.5f * v * (1.0f + th);
}

// ---------------------------------------------------------------------------
// 0) x fp32 -> bf16 cast
// ---------------------------------------------------------------------------
__global__ __launch_bounds__(256) void cast_kernel(
    const float4* __restrict__ s, ushort4* __restrict__ d)
{
    int i = blockIdx.x * 256 + threadIdx.x;
    float4 v = s[i];
    ushort4 o;
    o.x = f2bf(v.x); o.y = f2bf(v.y); o.z = f2bf(v.z); o.w = f2bf(v.w);
    d[i] = o;
}

// ---------------------------------------------------------------------------
// 1) Gating: fp64 accumulation so the top-K boundary ranking matches numpy
// ---------------------------------------------------------------------------
__global__ __launch_bounds__(256) void gating_kernel(
    const float* __restrict__ x, const float* __restrict__ wg,
    float* __restrict__ Sm)
{
    int wave = threadIdx.x >> 6;
    int lane = threadIdx.x & 63;
    int token = blockIdx.x * 4 + wave;
    int b = token >> 11, s = token & (Ss - 1);
    const float* xr = x + (size_t)token * Hh;

    double acc[Ee];
#pragma unroll
    for (int e = 0; e < Ee; ++e) acc[e] = 0.0;

    for (int i = 0; i < Hh / 64; ++i) {
        int h = lane + i * 64;
        double xv = (double)xr[h];
#pragma unroll
        for (int e = 0; e < Ee; ++e)
            acc[e] += xv * (double)wg[e * Hh + h];
    }
#pragma unroll
    for (int off = 32; off; off >>= 1) {
#pragma unroll
        for (int e = 0; e < Ee; ++e)
            acc[e] += __shfl_xor(acc[e], off, 64);
    }
    if (lane < Ee) {
        double m = acc[0];
#pragma unroll
        for (int e = 1; e < Ee; ++e) m = acc[e] > m ? acc[e] : m;
        double sum = 0.0;
#pragma unroll
        for (int e = 0; e < Ee; ++e) sum += exp(acc[e] - m);
        double v = exp(acc[lane] - m) / sum;
        Sm[((size_t)(b * Ee + lane)) * Ss + s] = (float)v;
    }
}

// ---------------------------------------------------------------------------
// 2) Top-K per (b,e): bitonic sort of 2048 keys; ties -> lower index first
// ---------------------------------------------------------------------------
__global__ __launch_bounds__(1024) void topk_kernel(
    const float* __restrict__ Sm, int* __restrict__ I, float* __restrict__ G)
{
    __shared__ unsigned long long keys[Ss];
    int be = blockIdx.x;
    const float* row = Sm + (size_t)be * Ss;
    for (int i = threadIdx.x; i < Ss; i += 1024) {
        unsigned int vb = __float_as_uint(row[i]);
        keys[i] = ((unsigned long long)vb << 32) | (unsigned int)(0xFFFFFFFFu - i);
    }
    __syncthreads();
    for (int k = 2; k <= Ss; k <<= 1) {
        for (int j = k >> 1; j > 0; j >>= 1) {
            for (int i = threadIdx.x; i < Ss; i += 1024) {
                int ixj = i ^ j;
                if (ixj > i) {
                    unsigned long long a = keys[i], c = keys[ixj];
                    bool desc = ((i & k) == 0);
                    if (desc ? (a < c) : (a > c)) { keys[i] = c; keys[ixj] = a; }
                }
            }
            __syncthreads();
        }
    }
    if (threadIdx.x < Kk) {
        unsigned long long kk = keys[threadIdx.x];
        I[(size_t)be * Kk + threadIdx.x] = (int)(0xFFFFFFFFu - (unsigned int)(kk & 0xFFFFFFFFu));
        G[(size_t)be * Kk + threadIdx.x] = __uint_as_float((unsigned int)(kk >> 32));
    }
}

// ---------------------------------------------------------------------------
// 3) Transpose + cast fp32 -> bf16, 64x64 tiles, coalesced 16B writes.
//    dst[z][c][r] = src[z][r][c]
// ---------------------------------------------------------------------------
__global__ __launch_bounds__(256) void transpose_cast_kernel(
    const float* __restrict__ src, unsigned short* __restrict__ dst, int R, int C)
{
    __shared__ float tile[64][68];   // stride 68: 16B-aligned rows, conflict-light
    int z = blockIdx.z;
    const float* s = src + (size_t)z * R * C;
    unsigned short* d = dst + (size_t)z * R * C;
    int c0 = blockIdx.x * 64, r0 = blockIdx.y * 64;
    int t = threadIdx.x;
#pragma unroll
    for (int p = 0; p < 4; ++p) {
        int g = p * 256 + t;
        int rr = g >> 4, cc = (g & 15) * 4;
        float4 v = *(const float4*)(s + (size_t)(r0 + rr) * C + c0 + cc);
        *(float4*)(&tile[rr][cc]) = v;
    }
    __syncthreads();
#pragma unroll
    for (int p = 0; p < 2; ++p) {
        int g = p * 256 + t;
        int cc = g >> 3, rr = (g & 7) * 8;
        u16x8 o;
#pragma unroll
        for (int k = 0; k < 8; ++k) o[k] = f2bf(tile[rr + k][cc]);
        *(u16x8*)(d + (size_t)(c0 + cc) * R + r0 + rr) = o;
    }
}

// ---------------------------------------------------------------------------
// GEMM: 128x128 tile, BK=64, 256 threads = 4 waves (2x2), 4x4 MFMA 16x16x32
// per wave.  LDS [128 rows][64 k] bf16, XOR-swizzled 16B granules:
// granule (r, cb) stored at (r, cb ^ (r&7)) -> fragment ds_read_b128 is
// bank-uniform (4 lanes/16B-position per half-wave = minimum), and the
// global_load_lds lane-contiguous destination stays legal.
// Staging per wave: 4 calls of 1024B; lane l, call c covers row
// w*32 + c*8 + (l>>3), source col granule (l&7) ^ ((l>>3)&7).
// Fragments: A/B [m|n = lane&15][k = quad*8+j]; C/D col=lane&15, row=quad*4+r.
// ---------------------------------------------------------------------------
#define BM 128
#define BN 128
#define BK 64

__global__ __launch_bounds__(256) void gemm1_kernel(
    const unsigned short* __restrict__ xb,   // [B,S,H] bf16
    const unsigned short* __restrict__ w1t,  // [E,F,H] bf16
    const float* __restrict__ b1, const int* __restrict__ I,
    unsigned short* __restrict__ h1,         // [gb,E,K,F] bf16
    int b0)
{
    __shared__ unsigned short As[BM * BK];   // 16 KB
    __shared__ unsigned short Bs[BN * BK];   // 16 KB
    const int e = blockIdx.z;
    const int y = blockIdx.y;
    const int b = b0 + (y >> 2), bl = y >> 2, tm = y & 3;
    const int tn = blockIdx.x;
    const int t = threadIdx.x;
    const int lane = t & 63, w = t >> 6;
    const int wm = (w & 1) * 64, wn = (w >> 1) * 64;
    const int fr = lane & 15, quad = lane >> 4;

    // staging coords
    const int sc = (((lane & 7) ^ ((lane >> 3) & 7)) * 8);   // col element offset
    const int rb = w * 32 + (lane >> 3);                      // row base (+ c*8)
    const int ib = (b * Ee + e) * Kk + tm * BM;
    const unsigned short* arow[4];
    const unsigned short* brow[4];
#pragma unroll
    for (int c = 0; c < 4; ++c) {
        int r = rb + c * 8;
        arow[c] = xb + ((size_t)(b * Ss + I[ib + r])) * Hh + sc;
        brow[c] = w1t + ((size_t)e * Ff + tn * BN + r) * Hh + sc;
    }
    char* asDst = (char*)As + w * 4096;
    char* bsDst = (char*)Bs + w * 4096;
    const char* Ab = (const char*)As;
    const char* Bbp = (const char*)Bs;

    f32x4 acc[4][4] = {};
    for (int k0 = 0; k0 < Hh; k0 += BK) {
#pragma unroll
        for (int c = 0; c < 4; ++c) async_copy16(arow[c] + k0, asDst + c * 1024);
#pragma unroll
        for (int c = 0; c < 4; ++c) async_copy16(brow[c] + k0, bsDst + c * 1024);
        __syncthreads();
#pragma unroll
        for (int ks = 0; ks < 2; ++ks) {
            const int sw = ((ks * 4 + quad) ^ (fr & 7)) << 4;
            bf16x8 a[4], bf[4];
#pragma unroll
            for (int i = 0; i < 4; ++i)
                a[i] = *(const bf16x8*)(Ab + ((wm + i * 16 + fr) << 7) + sw);
#pragma unroll
            for (int j = 0; j < 4; ++j)
                bf[j] = *(const bf16x8*)(Bbp + ((wn + j * 16 + fr) << 7) + sw);
#pragma unroll
            for (int i = 0; i < 4; ++i)
#pragma unroll
                for (int j = 0; j < 4; ++j)
                    acc[i][j] = __builtin_amdgcn_mfma_f32_16x16x32_bf16(a[i], bf[j], acc[i][j], 0, 0, 0);
        }
        __syncthreads();
    }

    float bias[4];
#pragma unroll
    for (int j = 0; j < 4; ++j)
        bias[j] = b1[e * Ff + tn * BN + wn + j * 16 + fr];
#pragma unroll
    for (int i = 0; i < 4; ++i) {
#pragma unroll
        for (int r = 0; r < 4; ++r) {
            int mm = tm * BM + wm + i * 16 + quad * 4 + r;
            unsigned short* orow = h1 + (((size_t)bl * Ee + e) * Kk + mm) * Ff + tn * BN + wn + fr;
#pragma unroll
            for (int j = 0; j < 4; ++j)
                orow[j * 16] = f2bf(gelu(acc[i][j][r] + bias[j]));
        }
    }
}

__global__ __launch_bounds__(256) void gemm2_kernel(
    const unsigned short* __restrict__ h1,   // [gb,E,K,F] bf16
    const unsigned short* __restrict__ w2t,  // [E,H,F] bf16
    const float* __restrict__ b2, const int* __restrict__ I, const float* __restrict__ G,
    float* __restrict__ out, int b0)
{
    __shared__ unsigned short As[BM * BK];
    __shared__ unsigned short Bs[BN * BK];
    const int e = blockIdx.z;
    const int y = blockIdx.y;
    const int b = b0 + (y >> 2), bl = y >> 2, tm = y & 3;
    const int tn = blockIdx.x;
    const int t = threadIdx.x;
    const int lane = t & 63, w = t >> 6;
    const int wm = (w & 1) * 64, wn = (w >> 1) * 64;
    const int fr = lane & 15, quad = lane >> 4;

    const int sc = (((lane & 7) ^ ((lane >> 3) & 7)) * 8);
    const int rb = w * 32 + (lane >> 3);
    const unsigned short* arow[4];
    const unsigned short* brow[4];
#pragma unroll
    for (int c = 0; c < 4; ++c) {
        int r = rb + c * 8;
        arow[c] = h1 + (((size_t)bl * Ee + e) * Kk + tm * BM + r) * Ff + sc;
        brow[c] = w2t + ((size_t)e * Hh + tn * BN + r) * Ff + sc;
    }
    char* asDst = (char*)As + w * 4096;
    char* bsDst = (char*)Bs + w * 4096;
    const char* Ab = (const char*)As;
    const char* Bbp = (const char*)Bs;

    f32x4 acc[4][4] = {};
    for (int k0 = 0; k0 < Ff; k0 += BK) {
#pragma unroll
        for (int c = 0; c < 4; ++c) async_copy16(arow[c] + k0, asDst + c * 1024);
#pragma unroll
        for (int c = 0; c < 4; ++c) async_copy16(brow[c] + k0, bsDst + c * 1024);
        __syncthreads();
#pragma unroll
        for (int ks = 0; ks < 2; ++ks) {
            const int sw = ((ks * 4 + quad) ^ (fr & 7)) << 4;
            bf16x8 a[4], bf[4];
#pragma unroll
            for (int i = 0; i < 4; ++i)
                a[i] = *(const bf16x8*)(Ab + ((wm + i * 16 + fr) << 7) + sw);
#pragma unroll
            for (int j = 0; j < 4; ++j)
                bf[j] = *(const bf16x8*)(Bbp + ((wn + j * 16 + fr) << 7) + sw);
#pragma unroll
            for (int i = 0; i < 4; ++i)
#pragma unroll
                for (int j = 0; j < 4; ++j)
                    acc[i][j] = __builtin_amdgcn_mfma_f32_16x16x32_bf16(a[i], bf[j], acc[i][j], 0, 0, 0);
        }
        __syncthreads();
    }

    float bias[4];
#pragma unroll
    for (int j = 0; j < 4; ++j)
        bias[j] = b2[e * Hh + tn * BN + wn + j * 16 + fr];
#pragma unroll
    for (int i = 0; i < 4; ++i) {
#pragma unroll
        for (int r = 0; r < 4; ++r) {
            int mm = tm * BM + wm + i * 16 + quad * 4 + r;
            int slot = (b * Ee + e) * Kk + mm;
            float gate = G[slot];
            int tok = I[slot];
            float* orow = out + ((size_t)(b * Ss + tok)) * Hh + tn * BN + wn + fr;
#pragma unroll
            for (int j = 0; j < 4; ++j)
                atomicAdd(&orow[j * 16], (acc[i][j][r] + bias[j]) * gate);
        }
    }
}

// ---------------------------------------------------------------------------
extern "C" void kernel_launch(void* const* d_in, const int* in_sizes, int n_in,
                              void* d_out, int out_size, void* d_ws, size_t ws_size,
                              hipStream_t stream) {
    const float* x  = (const float*)d_in[0];   // [B,S,H]
    const float* Wg = (const float*)d_in[1];   // [E,H]
    const float* W1 = (const float*)d_in[2];   // [E,H,F]
    const float* b1 = (const float*)d_in[3];   // [E,F]
    const float* W2 = (const float*)d_in[4];   // [E,F,H]
    const float* b2 = (const float*)d_in[5];   // [E,H]
    float* out = (float*)d_out;                // [B,S,H]

    size_t off = 0;
    char* base = (char*)d_ws;
    auto alloc = [&](size_t bytes) -> void* {
        void* p = base + off;
        off += (bytes + 255) & ~(size_t)255;
        return p;
    };
    float* Sm  = (float*)alloc((size_t)Bb * Ee * Ss * 4);
    int*   I   = (int*)alloc((size_t)Bb * Ee * Kk * 4);
    float* G   = (float*)alloc((size_t)Bb * Ee * Kk * 4);
    unsigned short* W1T = (unsigned short*)alloc((size_t)Ee * Ff * Hh * 2); // [E,F,H]
    unsigned short* W2T = (unsigned short*)alloc((size_t)Ee * Hh * Ff * 2); // [E,H,F]
    unsigned short* xb  = (unsigned short*)alloc((size_t)Bb * Ss * Hh * 2); // [B,S,H]
    size_t fixed = off;
    // adaptive batch-group size for h1 (deterministic: ws_size is constant)
    size_t h1_per_b = (size_t)Ee * Kk * Ff * 2;   // 32 MiB
    int gb = 4;
    while (gb > 1 && fixed + (size_t)gb * h1_per_b > ws_size) gb >>= 1;
    unsigned short* h1 = (unsigned short*)alloc((size_t)gb * h1_per_b);
    if (off > ws_size) return;

    hipMemsetAsync(d_out, 0, (size_t)out_size * sizeof(float), stream);

    cast_kernel<<<(Bb * Ss * Hh) / 1024, 256, 0, stream>>>((const float4*)x, (ushort4*)xb);
    gating_kernel<<<(Bb * Ss) / 4, 256, 0, stream>>>(x, Wg, Sm);
    topk_kernel<<<Bb * Ee, 1024, 0, stream>>>(Sm, I, G);
    transpose_cast_kernel<<<dim3(Ff / 64, Hh / 64, Ee), 256, 0, stream>>>(W1, W1T, Hh, Ff);
    transpose_cast_kernel<<<dim3(Hh / 64, Ff / 64, Ee), 256, 0, stream>>>(W2, W2T, Ff, Hh);

    for (int g = 0; g < Bb / gb; ++g) {
        gemm1_kernel<<<dim3(Ff / BN, 4 * gb, Ee), 256, 0, stream>>>(xb, W1T, b1, I, h1, g * gb);
        gemm2_kernel<<<dim3(Hh / BN, 4 * gb, Ee), 256, 0, stream>>>(h1, W2T, b2, I, G, out, g * gb);
    }
}